// Round 1
// baseline (266.606 us; speedup 1.0000x reference)
//
#include <hip/hip_runtime.h>
#include <stdint.h>
#include <stddef.h>

#define M_DIM 2048
#define N_DIM 4096
#define K_DIM 4352
#define H_DIM 1024
#define X_DIM 2304

// workspace layout (bytes)
#define A_OFF 0u
#define B_OFF 17825792u                 // 2048*4352*2
#define P_OFF 53477376u                 // B_OFF + 4096*4352*2
// total used: 87,031,808 bytes

typedef __bf16 bf16x8 __attribute__((ext_vector_type(8)));
typedef float f32x4 __attribute__((ext_vector_type(4)));

__device__ __forceinline__ unsigned short f32_to_bf16(float f) {
    unsigned u = __float_as_uint(f);
    u += 0x7FFFu + ((u >> 16) & 1u);     // round-to-nearest-even
    return (unsigned short)(u >> 16);
}

// ---------------------------------------------------------------------------
// Kernel 1: pack z = [x | prev_time | prev_layer] and W_all = [Wi;Wf;Wo;Ws]
// into bf16, row-major K-contiguous. rows 0..2047 -> A (z), 2048..6143 -> B (W).
// ---------------------------------------------------------------------------
__global__ __launch_bounds__(256) void convert_kernel(
    const float* __restrict__ x, const float* __restrict__ pt,
    const float* __restrict__ pl,
    const float* __restrict__ Wi, const float* __restrict__ Wf,
    const float* __restrict__ Wo, const float* __restrict__ Ws,
    unsigned short* __restrict__ Abf, unsigned short* __restrict__ Bbf)
{
    int col4 = blockIdx.x * 256 + threadIdx.x;   // float4 index within row
    if (col4 >= K_DIM / 4) return;
    int col = col4 * 4;
    int row = blockIdx.y;                        // 0..6143

    const float* src;
    unsigned short* dst;
    if (row < M_DIM) {
        if (col < X_DIM)             src = x  + (size_t)row * X_DIM + col;
        else if (col < X_DIM + H_DIM) src = pt + (size_t)row * H_DIM + (col - X_DIM);
        else                          src = pl + (size_t)row * H_DIM + (col - X_DIM - H_DIM);
        dst = Abf + (size_t)row * K_DIM + col;
    } else {
        int n = row - M_DIM;                     // 0..4095
        const float* W = (n < 1024) ? Wi : (n < 2048) ? Wf : (n < 3072) ? Wo : Ws;
        src = W + (size_t)(n & 1023) * K_DIM + col;
        dst = Bbf + (size_t)n * K_DIM + col;
    }
    float4 v = *(const float4*)src;
    union { unsigned short h[4]; uint64_t u; } r;
    r.h[0] = f32_to_bf16(v.x);
    r.h[1] = f32_to_bf16(v.y);
    r.h[2] = f32_to_bf16(v.z);
    r.h[3] = f32_to_bf16(v.w);
    *(uint64_t*)dst = r.u;
}

// ---------------------------------------------------------------------------
// Kernel 2: C[m,n] = sum_k A[m,k]*B[n,k]  (both K-contiguous, bf16 -> fp32)
// 128x128 tile, BK=64, 4 waves (2x2), each wave 64x64 via 4x4 mfma 16x16x32.
// global_load_lds width=16 staging, contiguous LDS (no padding).
// ---------------------------------------------------------------------------
__global__ __launch_bounds__(256) void gemm_bt(
    const unsigned short* __restrict__ A,   // [M_DIM, K_DIM]
    const unsigned short* __restrict__ B,   // [N_DIM, K_DIM]
    float* __restrict__ C)                  // [M_DIM, N_DIM]
{
    __shared__ unsigned short sA[128 * 64];
    __shared__ unsigned short sB[128 * 64];

    const int tid  = threadIdx.x;
    const int lane = tid & 63;
    const int wave = tid >> 6;
    const int wm = (wave >> 1) * 64;        // wave m-offset within tile
    const int wn = (wave & 1) * 64;         // wave n-offset within tile
    const int m0 = blockIdx.y * 128;
    const int n0 = blockIdx.x * 128;

    // staging: chunk c = i*256 + tid; row = c/8, col16 = c%8 (16B units)
    const int srow = tid >> 3;              // 0..31
    const int scol = (tid & 7) * 8;         // element column, 8 bf16 = 16 B

    // fragment coords: A[m=lane&15][k=(lane>>4)*8 + j]
    const int fr = lane & 15;
    const int fk = (lane >> 4) * 8;

    f32x4 acc[4][4];
#pragma unroll
    for (int i = 0; i < 4; ++i)
#pragma unroll
        for (int j = 0; j < 4; ++j) acc[i][j] = (f32x4){0.f, 0.f, 0.f, 0.f};

    const unsigned short* Ab = A + (size_t)(m0 + srow) * K_DIM + scol;
    const unsigned short* Bb = B + (size_t)(n0 + srow) * K_DIM + scol;

    for (int kt = 0; kt < K_DIM; kt += 64) {
        __syncthreads();   // previous compute done before overwriting LDS
#pragma unroll
        for (int i = 0; i < 4; ++i) {
            __builtin_amdgcn_global_load_lds(
                (const __attribute__((address_space(1))) unsigned*)(Ab + (size_t)i * 32 * K_DIM + kt),
                (__attribute__((address_space(3))) unsigned*)((char*)sA + i * 4096 + wave * 1024),
                16, 0, 0);
            __builtin_amdgcn_global_load_lds(
                (const __attribute__((address_space(1))) unsigned*)(Bb + (size_t)i * 32 * K_DIM + kt),
                (__attribute__((address_space(3))) unsigned*)((char*)sB + i * 4096 + wave * 1024),
                16, 0, 0);
        }
        __syncthreads();   // emits s_waitcnt vmcnt(0) -> staging complete

#pragma unroll
        for (int kk = 0; kk < 64; kk += 32) {
            bf16x8 af[4], bfr[4];
#pragma unroll
            for (int i = 0; i < 4; ++i) {
                af[i]  = *(const bf16x8*)(sA + (wm + i * 16 + fr) * 64 + kk + fk);
                bfr[i] = *(const bf16x8*)(sB + (wn + i * 16 + fr) * 64 + kk + fk);
            }
#pragma unroll
            for (int i = 0; i < 4; ++i)
#pragma unroll
                for (int j = 0; j < 4; ++j)
                    acc[i][j] = __builtin_amdgcn_mfma_f32_16x16x32_bf16(
                        af[i], bfr[j], acc[i][j], 0, 0, 0);
        }
    }

    // C/D layout (m89-verified): col = lane&15, row = (lane>>4)*4 + reg
    const int crow = m0 + wm + (lane >> 4) * 4;
    const int ccol = n0 + wn + (lane & 15);
#pragma unroll
    for (int i = 0; i < 4; ++i)
#pragma unroll
        for (int j = 0; j < 4; ++j) {
            float* cp = C + (size_t)(crow + i * 16) * N_DIM + (ccol + j * 16);
#pragma unroll
            for (int r = 0; r < 4; ++r) cp[(size_t)r * N_DIM] = acc[i][j][r];
        }
}

// ---------------------------------------------------------------------------
// Kernel 3: gates + state update, float4-vectorized over [2048, 1024]
// ---------------------------------------------------------------------------
__device__ __forceinline__ float sigm_(float x) { return 1.f / (1.f + __expf(-x)); }
__device__ __forceinline__ float tanh_(float x) {
    x = fminf(15.f, fmaxf(-15.f, x));
    float e = __expf(2.f * x);
    return (e - 1.f) / (e + 1.f);
}

__global__ __launch_bounds__(256) void epilogue_kernel(
    const float* __restrict__ proj,       // [2048, 4096]
    const float* __restrict__ old_state,  // [2048, 1024]
    const float* __restrict__ bi, const float* __restrict__ bfv,
    const float* __restrict__ bo, const float* __restrict__ bs,
    float* __restrict__ out)              // [2048, 1024]
{
    int idx = blockIdx.x * 256 + threadIdx.x;    // 0 .. 2048*256-1
    int m  = idx >> 8;                           // row
    int h4 = idx & 255;                          // float4 col within H

    const float4* prow = (const float4*)(proj + (size_t)m * N_DIM);
    float4 gi = prow[h4];
    float4 gf = prow[256 + h4];
    float4 go = prow[512 + h4];
    float4 gs = prow[768 + h4];
    float4 vbi = ((const float4*)bi)[h4];
    float4 vbf = ((const float4*)bfv)[h4];
    float4 vbo = ((const float4*)bo)[h4];
    float4 vbs = ((const float4*)bs)[h4];
    float4 old = ((const float4*)old_state)[(size_t)m * 256 + h4];

    float4 o;
    {
        float ig = sigm_(gi.x + vbi.x), fg = sigm_(gf.x + vbf.x);
        float og = sigm_(go.x + vbo.x), ts = tanh_(gs.x + vbs.x);
        o.x = og * tanh_(fg * old.x + ig * ts);
    }
    {
        float ig = sigm_(gi.y + vbi.y), fg = sigm_(gf.y + vbf.y);
        float og = sigm_(go.y + vbo.y), ts = tanh_(gs.y + vbs.y);
        o.y = og * tanh_(fg * old.y + ig * ts);
    }
    {
        float ig = sigm_(gi.z + vbi.z), fg = sigm_(gf.z + vbf.z);
        float og = sigm_(go.z + vbo.z), ts = tanh_(gs.z + vbs.z);
        o.z = og * tanh_(fg * old.z + ig * ts);
    }
    {
        float ig = sigm_(gi.w + vbi.w), fg = sigm_(gf.w + vbf.w);
        float og = sigm_(go.w + vbo.w), ts = tanh_(gs.w + vbs.w);
        o.w = og * tanh_(fg * old.w + ig * ts);
    }
    ((float4*)out)[(size_t)m * 256 + h4] = o;
}

// ---------------------------------------------------------------------------
extern "C" void kernel_launch(void* const* d_in, const int* in_sizes, int n_in,
                              void* d_out, int out_size, void* d_ws, size_t ws_size,
                              hipStream_t stream) {
    const float* x   = (const float*)d_in[0];
    const float* pt  = (const float*)d_in[1];
    const float* pl  = (const float*)d_in[2];
    const float* old = (const float*)d_in[3];
    const float* Wi  = (const float*)d_in[4];
    const float* bi  = (const float*)d_in[5];
    const float* Wf  = (const float*)d_in[6];
    const float* bf  = (const float*)d_in[7];
    const float* Wo  = (const float*)d_in[8];
    const float* bo  = (const float*)d_in[9];
    const float* Ws  = (const float*)d_in[10];
    const float* bs  = (const float*)d_in[11];
    float* out = (float*)d_out;

    char* ws = (char*)d_ws;
    unsigned short* Abf = (unsigned short*)(ws + A_OFF);
    unsigned short* Bbf = (unsigned short*)(ws + B_OFF);
    float*          prj = (float*)(ws + P_OFF);

    // 1) pack/convert: 6144 rows x 1088 float4
    dim3 cgrid((K_DIM / 4 + 255) / 256, M_DIM + N_DIM);
    convert_kernel<<<cgrid, 256, 0, stream>>>(x, pt, pl, Wi, Wf, Wo, Ws, Abf, Bbf);

    // 2) GEMM: 32 n-tiles x 16 m-tiles
    dim3 ggrid(N_DIM / 128, M_DIM / 128);
    gemm_bt<<<ggrid, 256, 0, stream>>>(Abf, Bbf, prj);

    // 3) epilogue
    epilogue_kernel<<<(M_DIM * H_DIM / 4) / 256, 256, 0, stream>>>(
        prj, old, bi, bf, bo, bs, out);
}